// Round 5
// baseline (212.558 us; speedup 1.0000x reference)
//
#include <hip/hip_runtime.h>

#define B_SZ 256
#define D_SZ 256
#define M_SZ 65536
#define C_SZ 1000
#define TEMP 0.05f
#define EPSF 1e-6f

#define NBLK_SORT 32
#define CHUNK (M_SZ / NBLK_SORT)   // 2048 labels per sort block

// ---- ws layout (bytes) ----
#define OFF_FCT     0          // float[D_SZ*C_SZ] = 1,024,000 B (transposed, pre-scaled)
#define OFF_NUMS    1024000    // int[C_SZ]
#define OFF_OFFS    1028000    // int[C_SZ]
#define OFF_ACC     1032000    // float[2]
#define OFF_LCNT    1032008    // int[1] loss ticket
#define OFF_CSTK    1032012    // int[1] classsum ticket
#define OFF_COUNTS  1032064    // int[NBLK_SORT*C_SZ] = 128,000 B
#define OFF_MEMB    1160064    // int[M_SZ] = 262,144 B (end 1,422,208)

// Pass 1: per-block private LDS histogram (no global atomics). Block 0 zeroes
// all cross-kernel control state for this call (visible via kernel boundary).
__launch_bounds__(1024)
__global__ void k_hist(const int* __restrict__ labels, int* __restrict__ counts,
                       float* __restrict__ acc, int* __restrict__ lcnt,
                       int* __restrict__ cstk) {
    __shared__ int h[C_SZ];
    int t = threadIdx.x, b = blockIdx.x;
    if (t < C_SZ) h[t] = 0;
    if (b == 0 && t == 0) { acc[0] = 0.f; acc[1] = 0.f; lcnt[0] = 0; cstk[0] = 0; }
    __syncthreads();
    int start = b * CHUNK;
    #pragma unroll
    for (int k = 0; k < CHUNK / 1024; ++k)
        atomicAdd(&h[labels[start + k * 1024 + t]], 1);  // LDS atomic
    __syncthreads();
    if (t < C_SZ) counts[b * C_SZ + t] = h[t];
}

// Pass 2: scatter; each block REDUNDANTLY computes the global scan (cheap,
// parallel) so no single-block scan kernel is needed. Block 0 publishes
// nums/offs for k_mega.
__launch_bounds__(1024)
__global__ void k_scatter(const int* __restrict__ labels, const int* __restrict__ counts,
                          int* __restrict__ nums, int* __restrict__ offs,
                          int* __restrict__ members) {
    __shared__ int sc[1024];
    __shared__ int cur[C_SZ];
    int t = threadIdx.x, b = blockIdx.x;
    int tot = 0, mybase = 0;
    if (t < C_SZ) {
        #pragma unroll
        for (int bb = 0; bb < NBLK_SORT; ++bb) {
            int v = counts[bb * C_SZ + t];
            tot += v;
            if (bb < b) mybase += v;
        }
    }
    sc[t] = tot;
    __syncthreads();
    for (int d = 1; d < 1024; d <<= 1) {
        int v = (t >= d) ? sc[t - d] : 0;
        __syncthreads();
        sc[t] += v;
        __syncthreads();
    }
    if (t < C_SZ) {
        int e = sc[t] - tot;  // exclusive scan = class base
        cur[t] = e + mybase;  // this block's write cursor for class t
        if (b == 0) { nums[t] = tot; offs[t] = e; }
    }
    __syncthreads();
    int start = b * CHUNK;
    #pragma unroll
    for (int k = 0; k < CHUNK / 1024; ++k) {
        int m = start + k * 1024 + t;
        int pos = atomicAdd(&cur[labels[m]], 1);  // LDS atomic
        members[pos] = m;
    }
}

// Fused classsum + loss. 256 blocks x 1024 threads (16 waves -> 2 blocks/CU
// capacity, so ALL blocks co-resident: the spin below cannot deadlock).
// Phase A: subgroup g = t>>8 sums class c = bid*4+g (mask c<1000), writes
//          fct[d*1000+c] pre-scaled; device-scope release + ticket.
// Phase B: blocks 0-127 spin for ticket==256, acquire, then the proven
//          2-rows-per-block loss with ticket-fused finalize.
__launch_bounds__(1024)
__global__ void k_mega(const float* __restrict__ features,
                       const int* __restrict__ members,
                       const int* __restrict__ offs,
                       const int* __restrict__ nums,
                       const float* __restrict__ feat,
                       const float* __restrict__ soft,
                       const int* __restrict__ indexes,
                       const int* __restrict__ labels,
                       const int* __restrict__ bil,
                       const int* __restrict__ cur_epoch,
                       float* __restrict__ fct,
                       float* __restrict__ acc, int* __restrict__ lcnt,
                       int* __restrict__ cstk, float* __restrict__ out) {
    __shared__ float xs0[D_SZ], xs1[D_SZ];
    __shared__ float wred[16], wred2[16];
    __shared__ float bc0, bc1;
    __shared__ int tgt0, tgt1, sr0, sr1;

    int t = threadIdx.x;
    int bid = blockIdx.x;

    // ---- Phase A: class-sum for c = bid*4 + (t>>8), dim tt = t&255 ----
    {
        int g = t >> 8, tt = t & 255;
        int c = bid * 4 + g;
        if (c < C_SZ) {
            int beg = offs[c], n = nums[c];
            float a0 = 0.f, a1 = 0.f, a2 = 0.f, a3 = 0.f;
            float a4 = 0.f, a5 = 0.f, a6 = 0.f, a7 = 0.f;
            int i = 0;
            for (; i + 8 <= n; i += 8) {
                int r0 = members[beg + i + 0];
                int r1 = members[beg + i + 1];
                int r2 = members[beg + i + 2];
                int r3 = members[beg + i + 3];
                int r4 = members[beg + i + 4];
                int r5 = members[beg + i + 5];
                int r6 = members[beg + i + 6];
                int r7 = members[beg + i + 7];
                a0 += features[(size_t)r0 * D_SZ + tt];
                a1 += features[(size_t)r1 * D_SZ + tt];
                a2 += features[(size_t)r2 * D_SZ + tt];
                a3 += features[(size_t)r3 * D_SZ + tt];
                a4 += features[(size_t)r4 * D_SZ + tt];
                a5 += features[(size_t)r5 * D_SZ + tt];
                a6 += features[(size_t)r6 * D_SZ + tt];
                a7 += features[(size_t)r7 * D_SZ + tt];
            }
            for (; i < n; ++i) a0 += features[(size_t)members[beg + i] * D_SZ + tt];
            float s = ((a0 + a1) + (a2 + a3)) + ((a4 + a5) + (a6 + a7));
            float scale = 1.0f / (TEMP * (float)(n > 0 ? n : 1));
            fct[(size_t)tt * C_SZ + c] = s * scale;
        }
    }
    __threadfence();            // device-scope release of this thread's fct stores
    __syncthreads();            // all block stores fenced before ticket
    if (t == 0) atomicAdd(cstk, 1);

    if (bid >= B_SZ / 2) return;   // blocks 128-255 done

    // ---- device barrier: wait for all 256 classsum tickets ----
    if (t == 0) {
        while (__hip_atomic_load(cstk, __ATOMIC_RELAXED, __HIP_MEMORY_SCOPE_AGENT) < 256)
            __builtin_amdgcn_s_sleep(2);
    }
    __syncthreads();
    __threadfence();            // acquire side: invalidate stale cached fct

    // ---- Phase B: loss for rows 2*bid, 2*bid+1 ----
    int lane = t & 63, wid = t >> 6;
    int r0 = bid * 2;

    if (t == 0) {
        tgt0 = labels[indexes[r0]];
        tgt1 = labels[indexes[r0 + 1]];
        sr0 = bil[r0];
        sr1 = bil[r0 + 1];
    }

    float v = (t < 512) ? feat[(size_t)r0 * D_SZ + t] : 0.f;
    float s = v * v;
    #pragma unroll
    for (int o = 32; o; o >>= 1) s += __shfl_down(s, o);
    if (lane == 0) wred[wid] = s;  // waves 0-3 = row0, 4-7 = row1
    __syncthreads();
    if (t == 0) {
        bc0 = fmaxf(sqrtf(wred[0] + wred[1] + wred[2] + wred[3]), 1e-12f);
        bc1 = fmaxf(sqrtf(wred[4] + wred[5] + wred[6] + wred[7]), 1e-12f);
    }
    __syncthreads();
    if (t < 256) xs0[t] = v / bc0;
    else if (t < 512) xs1[t - 256] = v / bc1;
    __syncthreads();

    float a0 = 0.f, a1 = 0.f;
    if (t < C_SZ) {
        #pragma unroll 8
        for (int i = 0; i < D_SZ; ++i) {
            float f = fct[(size_t)i * C_SZ + t];  // coalesced across lanes
            a0 = fmaf(xs0[i], f, a0);
            a1 = fmaf(xs1[i], f, a1);
        }
    }
    float mk = (t < C_SZ && nums[t] > 0) ? 1.f : 0.f;
    float e0 = mk * __expf(a0);
    float e1 = mk * __expf(a1);

    float s0 = e0, s1 = e1;
    #pragma unroll
    for (int o = 32; o; o >>= 1) {
        s0 += __shfl_down(s0, o);
        s1 += __shfl_down(s1, o);
    }
    if (lane == 0) { wred[wid] = s0; wred2[wid] = s1; }
    __syncthreads();
    if (t == 0) {
        float z0 = 0.f, z1 = 0.f;
        #pragma unroll
        for (int i = 0; i < 16; ++i) { z0 += wred[i]; z1 += wred2[i]; }
        bc0 = z0; bc1 = z1;
    }
    __syncthreads();
    float inv0 = 1.0f / (bc0 + EPSF);
    float inv1 = 1.0f / (bc1 + EPSF);

    float p1 = 0.f, p2 = 0.f;
    if (t < C_SZ) {
        float lp0 = __logf(e0 * inv0 + EPSF);
        float lp1 = __logf(e1 * inv1 + EPSF);
        p2 = -(soft[(size_t)sr0 * C_SZ + t] * lp0 + soft[(size_t)sr1 * C_SZ + t] * lp1);
        if (t == tgt0) p1 -= lp0;
        if (t == tgt1) p1 -= lp1;
    }
    #pragma unroll
    for (int o = 32; o; o >>= 1) {
        p1 += __shfl_down(p1, o);
        p2 += __shfl_down(p2, o);
    }
    __syncthreads();
    if (lane == 0) { wred[wid] = p1; wred2[wid] = p2; }
    __syncthreads();
    if (t == 0) {
        float z1 = 0.f, z2 = 0.f;
        #pragma unroll
        for (int i = 0; i < 16; ++i) { z1 += wred[i]; z2 += wred2[i]; }
        atomicAdd(&acc[0], z1);
        atomicAdd(&acc[1], z2);
        __threadfence();
        int done = atomicAdd(lcnt, 1);
        if (done == B_SZ / 2 - 1) {
            float l1 = atomicAdd(&acc[0], 0.f) / (float)B_SZ;
            float l2 = atomicAdd(&acc[1], 0.f) / (float)B_SZ;
            out[0] = (cur_epoch[0] == 0) ? l1 : 0.5f * (l1 + l2);
        }
    }
}

extern "C" void kernel_launch(void* const* d_in, const int* in_sizes, int n_in,
                              void* d_out, int out_size, void* d_ws, size_t ws_size,
                              hipStream_t stream) {
    const float* feat     = (const float*)d_in[0];
    const float* features = (const float*)d_in[1];
    const float* soft     = (const float*)d_in[2];
    const int* indexes    = (const int*)d_in[3];
    const int* labels     = (const int*)d_in[4];
    const int* bil        = (const int*)d_in[5];
    const int* cur_epoch  = (const int*)d_in[6];

    char* ws = (char*)d_ws;
    float* fct   = (float*)(ws + OFF_FCT);
    int* nums    = (int*)(ws + OFF_NUMS);
    int* offs    = (int*)(ws + OFF_OFFS);
    float* acc   = (float*)(ws + OFF_ACC);
    int* lcnt    = (int*)(ws + OFF_LCNT);
    int* cstk    = (int*)(ws + OFF_CSTK);
    int* counts  = (int*)(ws + OFF_COUNTS);
    int* members = (int*)(ws + OFF_MEMB);

    k_hist<<<NBLK_SORT, 1024, 0, stream>>>(labels, counts, acc, lcnt, cstk);
    k_scatter<<<NBLK_SORT, 1024, 0, stream>>>(labels, counts, nums, offs, members);
    k_mega<<<256, 1024, 0, stream>>>(features, members, offs, nums, feat, soft,
                                     indexes, labels, bil, cur_epoch, fct, acc,
                                     lcnt, cstk, (float*)d_out);
}

// Round 6
// 70.127 us; speedup vs baseline: 3.0310x; 3.0310x over previous
//
#include <hip/hip_runtime.h>

#define B_SZ 256
#define D_SZ 256
#define M_SZ 65536
#define C_SZ 1000
#define TEMP 0.05f
#define EPSF 1e-6f

#define NBLK_SORT 32
#define CHUNK (M_SZ / NBLK_SORT)   // 2048 labels per sort block

// ---- ws layout (bytes) ----
#define OFF_FCT     0          // float[D_SZ*C_SZ] = 1,024,000 B (transposed, pre-scaled)
#define OFF_NUMS    1024000    // int[C_SZ]
#define OFF_OFFS    1028000    // int[C_SZ]
#define OFF_ACC     1032000    // float[2]
#define OFF_LCNT    1032008    // int[1] loss ticket
#define OFF_COUNTS  1032064    // int[NBLK_SORT*C_SZ] = 128,000 B
#define OFF_MEMB    1160064    // int[M_SZ] = 262,144 B (end 1,422,208)

// Pass 1: per-block private LDS histogram (no global atomics). Block 0 zeroes
// cross-kernel accumulators (visible to later kernels via kernel boundary).
__launch_bounds__(1024)
__global__ void k_hist(const int* __restrict__ labels, int* __restrict__ counts,
                       float* __restrict__ acc, int* __restrict__ lcnt) {
    __shared__ int h[C_SZ];
    int t = threadIdx.x, b = blockIdx.x;
    if (t < C_SZ) h[t] = 0;
    if (b == 0 && t == 0) { acc[0] = 0.f; acc[1] = 0.f; lcnt[0] = 0; }
    __syncthreads();
    int start = b * CHUNK;
    #pragma unroll
    for (int k = 0; k < CHUNK / 1024; ++k)
        atomicAdd(&h[labels[start + k * 1024 + t]], 1);  // LDS atomic
    __syncthreads();
    if (t < C_SZ) counts[b * C_SZ + t] = h[t];
}

// Pass 2: scatter; each block redundantly computes the global scan (parallel,
// cheap) so no single-block scan dispatch. Block 0 publishes nums/offs.
__launch_bounds__(1024)
__global__ void k_scatter(const int* __restrict__ labels, const int* __restrict__ counts,
                          int* __restrict__ nums, int* __restrict__ offs,
                          int* __restrict__ members) {
    __shared__ int sc[1024];
    __shared__ int cur[C_SZ];
    int t = threadIdx.x, b = blockIdx.x;
    int tot = 0, mybase = 0;
    if (t < C_SZ) {
        #pragma unroll
        for (int bb = 0; bb < NBLK_SORT; ++bb) {
            int v = counts[bb * C_SZ + t];
            tot += v;
            if (bb < b) mybase += v;
        }
    }
    sc[t] = tot;
    __syncthreads();
    for (int d = 1; d < 1024; d <<= 1) {
        int v = (t >= d) ? sc[t - d] : 0;
        __syncthreads();
        sc[t] += v;
        __syncthreads();
    }
    if (t < C_SZ) {
        int e = sc[t] - tot;
        cur[t] = e + mybase;
        if (b == 0) { nums[t] = tot; offs[t] = e; }
    }
    __syncthreads();
    int start = b * CHUNK;
    #pragma unroll
    for (int k = 0; k < CHUNK / 1024; ++k) {
        int m = start + k * 1024 + t;
        int pos = atomicAdd(&cur[labels[m]], 1);  // LDS atomic
        members[pos] = m;
    }
}

// One block per class: sum member rows, 8-way unrolled for MLP. Writes
// transposed + pre-scaled: fct[d*C + c] = sum / (TEMP * max(n,1)).
__launch_bounds__(256)
__global__ void k_classsum(const float* __restrict__ features,
                           const int* __restrict__ members,
                           const int* __restrict__ offs,
                           const int* __restrict__ nums,
                           float* __restrict__ fct) {
    int c = blockIdx.x;
    int t = threadIdx.x;
    int beg = offs[c], n = nums[c];
    float a0 = 0.f, a1 = 0.f, a2 = 0.f, a3 = 0.f;
    float a4 = 0.f, a5 = 0.f, a6 = 0.f, a7 = 0.f;
    int i = 0;
    for (; i + 8 <= n; i += 8) {
        int r0 = members[beg + i + 0];
        int r1 = members[beg + i + 1];
        int r2 = members[beg + i + 2];
        int r3 = members[beg + i + 3];
        int r4 = members[beg + i + 4];
        int r5 = members[beg + i + 5];
        int r6 = members[beg + i + 6];
        int r7 = members[beg + i + 7];
        a0 += features[(size_t)r0 * D_SZ + t];
        a1 += features[(size_t)r1 * D_SZ + t];
        a2 += features[(size_t)r2 * D_SZ + t];
        a3 += features[(size_t)r3 * D_SZ + t];
        a4 += features[(size_t)r4 * D_SZ + t];
        a5 += features[(size_t)r5 * D_SZ + t];
        a6 += features[(size_t)r6 * D_SZ + t];
        a7 += features[(size_t)r7 * D_SZ + t];
    }
    for (; i < n; ++i) a0 += features[(size_t)members[beg + i] * D_SZ + t];
    float s = ((a0 + a1) + (a2 + a3)) + ((a4 + a5) + (a6 + a7));
    float scale = 1.0f / (TEMP * (float)(n > 0 ? n : 1));
    fct[(size_t)t * C_SZ + c] = s * scale;
}

// 32 blocks x 1024 thr; block handles 8 rows. Thread t: class-quad
// c0 = 4*(t&255) (active for t&255 < 250), row pair (2*rh, 2*rh+1), rh=t>>8.
// fct read as aligned float4 (wave reads 1KB contiguous), xs as ds_read_b128.
__launch_bounds__(1024)
__global__ void k_loss(const float* __restrict__ feat,
                       const float* __restrict__ fct,
                       const int* __restrict__ nums,
                       const float* __restrict__ soft,
                       const int* __restrict__ indexes,
                       const int* __restrict__ labels,
                       const int* __restrict__ bil,
                       const int* __restrict__ cur_epoch,
                       float* __restrict__ acc, int* __restrict__ lcnt,
                       float* __restrict__ out) {
    __shared__ float xs[8][D_SZ];      // 8 KB
    __shared__ float dred[16][2];
    __shared__ float denomS[8];
    __shared__ float wred[16], wred2[16];
    __shared__ int tgtA[8], srA[8];

    int t = threadIdx.x;
    int lane = t & 63, wid = t >> 6;
    int r0 = blockIdx.x * 8;

    // ---- normalize: wave w (w<8) owns row w; lane loads float4 ----
    if (wid < 8) {
        float4 v4 = *(const float4*)&feat[(size_t)(r0 + wid) * D_SZ + lane * 4];
        float s = v4.x * v4.x + v4.y * v4.y + v4.z * v4.z + v4.w * v4.w;
        #pragma unroll
        for (int o = 32; o; o >>= 1) s += __shfl_down(s, o);
        float nrm = fmaxf(sqrtf(__shfl(s, 0)), 1e-12f);
        float inv = 1.0f / nrm;
        *(float4*)&xs[wid][lane * 4] =
            make_float4(v4.x * inv, v4.y * inv, v4.z * inv, v4.w * inv);
    }
    if (t < 8) {
        tgtA[t] = labels[indexes[r0 + t]];
        srA[t] = bil[r0 + t];
    }
    __syncthreads();

    int tt = t & 255;
    int rh = t >> 8;
    int c0 = 4 * tt;                 // class-quad base
    bool active = (c0 < C_SZ);       // tt < 250
    int row0 = 2 * rh, row1 = 2 * rh + 1;

    // ---- sim: acc[2 rows][4 classes] ----
    float a00 = 0.f, a01 = 0.f, a02 = 0.f, a03 = 0.f;
    float a10 = 0.f, a11 = 0.f, a12 = 0.f, a13 = 0.f;
    for (int i = 0; i < D_SZ; i += 4) {
        float4 xa = *(const float4*)&xs[row0][i];   // ds_read_b128
        float4 xb = *(const float4*)&xs[row1][i];   // ds_read_b128
        #pragma unroll
        for (int u = 0; u < 4; ++u) {
            float4 f4 = active ? *(const float4*)&fct[(size_t)(i + u) * C_SZ + c0]
                               : make_float4(0.f, 0.f, 0.f, 0.f);
            float xau = (u == 0) ? xa.x : (u == 1) ? xa.y : (u == 2) ? xa.z : xa.w;
            float xbu = (u == 0) ? xb.x : (u == 1) ? xb.y : (u == 2) ? xb.z : xb.w;
            a00 = fmaf(xau, f4.x, a00); a01 = fmaf(xau, f4.y, a01);
            a02 = fmaf(xau, f4.z, a02); a03 = fmaf(xau, f4.w, a03);
            a10 = fmaf(xbu, f4.x, a10); a11 = fmaf(xbu, f4.y, a11);
            a12 = fmaf(xbu, f4.z, a12); a13 = fmaf(xbu, f4.w, a13);
        }
    }

    // ---- masked exp ----
    float m0 = 0.f, m1 = 0.f, m2 = 0.f, m3 = 0.f;
    if (active) {
        int4 nm = *(const int4*)&nums[c0];
        m0 = nm.x > 0 ? 1.f : 0.f; m1 = nm.y > 0 ? 1.f : 0.f;
        m2 = nm.z > 0 ? 1.f : 0.f; m3 = nm.w > 0 ? 1.f : 0.f;
    }
    float e00 = m0 * __expf(a00), e01 = m1 * __expf(a01);
    float e02 = m2 * __expf(a02), e03 = m3 * __expf(a03);
    float e10 = m0 * __expf(a10), e11 = m1 * __expf(a11);
    float e12 = m2 * __expf(a12), e13 = m3 * __expf(a13);
    if (!active) {
        e00 = e01 = e02 = e03 = 0.f;
        e10 = e11 = e12 = e13 = 0.f;
    }

    // ---- per-row denominators ----
    float s0 = (e00 + e01) + (e02 + e03);
    float s1 = (e10 + e11) + (e12 + e13);
    #pragma unroll
    for (int o = 32; o; o >>= 1) {
        s0 += __shfl_down(s0, o);
        s1 += __shfl_down(s1, o);
    }
    if (lane == 0) { dred[wid][0] = s0; dred[wid][1] = s1; }
    __syncthreads();
    if (t < 8) {
        int g = t >> 1, j = t & 1;   // row t = 2g + j, owned by waves 4g..4g+3
        denomS[t] = ((dred[4 * g][j] + dred[4 * g + 1][j]) +
                     (dred[4 * g + 2][j] + dred[4 * g + 3][j]));
    }
    __syncthreads();
    float inv0 = 1.0f / (denomS[row0] + EPSF);
    float inv1 = 1.0f / (denomS[row1] + EPSF);

    // ---- loss partials ----
    float p1 = 0.f, p2 = 0.f;
    if (active) {
        int tg0 = tgtA[row0], tg1 = tgtA[row1];
        float4 sp0 = *(const float4*)&soft[(size_t)srA[row0] * C_SZ + c0];
        float4 sp1 = *(const float4*)&soft[(size_t)srA[row1] * C_SZ + c0];
        float lp;
        lp = __logf(e00 * inv0 + EPSF); p2 -= sp0.x * lp; if (c0 + 0 == tg0) p1 -= lp;
        lp = __logf(e01 * inv0 + EPSF); p2 -= sp0.y * lp; if (c0 + 1 == tg0) p1 -= lp;
        lp = __logf(e02 * inv0 + EPSF); p2 -= sp0.z * lp; if (c0 + 2 == tg0) p1 -= lp;
        lp = __logf(e03 * inv0 + EPSF); p2 -= sp0.w * lp; if (c0 + 3 == tg0) p1 -= lp;
        lp = __logf(e10 * inv1 + EPSF); p2 -= sp1.x * lp; if (c0 + 0 == tg1) p1 -= lp;
        lp = __logf(e11 * inv1 + EPSF); p2 -= sp1.y * lp; if (c0 + 1 == tg1) p1 -= lp;
        lp = __logf(e12 * inv1 + EPSF); p2 -= sp1.z * lp; if (c0 + 2 == tg1) p1 -= lp;
        lp = __logf(e13 * inv1 + EPSF); p2 -= sp1.w * lp; if (c0 + 3 == tg1) p1 -= lp;
    }
    #pragma unroll
    for (int o = 32; o; o >>= 1) {
        p1 += __shfl_down(p1, o);
        p2 += __shfl_down(p2, o);
    }
    __syncthreads();
    if (lane == 0) { wred[wid] = p1; wred2[wid] = p2; }
    __syncthreads();
    if (t == 0) {
        float z1 = 0.f, z2 = 0.f;
        #pragma unroll
        for (int i = 0; i < 16; ++i) { z1 += wred[i]; z2 += wred2[i]; }
        atomicAdd(&acc[0], z1);
        atomicAdd(&acc[1], z2);
        __threadfence();
        int done = atomicAdd(lcnt, 1);
        if (done == (int)gridDim.x - 1) {
            float l1 = atomicAdd(&acc[0], 0.f) / (float)B_SZ;
            float l2 = atomicAdd(&acc[1], 0.f) / (float)B_SZ;
            out[0] = (cur_epoch[0] == 0) ? l1 : 0.5f * (l1 + l2);
        }
    }
}

extern "C" void kernel_launch(void* const* d_in, const int* in_sizes, int n_in,
                              void* d_out, int out_size, void* d_ws, size_t ws_size,
                              hipStream_t stream) {
    const float* feat     = (const float*)d_in[0];
    const float* features = (const float*)d_in[1];
    const float* soft     = (const float*)d_in[2];
    const int* indexes    = (const int*)d_in[3];
    const int* labels     = (const int*)d_in[4];
    const int* bil        = (const int*)d_in[5];
    const int* cur_epoch  = (const int*)d_in[6];

    char* ws = (char*)d_ws;
    float* fct   = (float*)(ws + OFF_FCT);
    int* nums    = (int*)(ws + OFF_NUMS);
    int* offs    = (int*)(ws + OFF_OFFS);
    float* acc   = (float*)(ws + OFF_ACC);
    int* lcnt    = (int*)(ws + OFF_LCNT);
    int* counts  = (int*)(ws + OFF_COUNTS);
    int* members = (int*)(ws + OFF_MEMB);

    k_hist<<<NBLK_SORT, 1024, 0, stream>>>(labels, counts, acc, lcnt);
    k_scatter<<<NBLK_SORT, 1024, 0, stream>>>(labels, counts, nums, offs, members);
    k_classsum<<<C_SZ, 256, 0, stream>>>(features, members, offs, nums, fct);
    k_loss<<<B_SZ / 8, 1024, 0, stream>>>(feat, fct, nums, soft, indexes, labels,
                                          bil, cur_epoch, acc, lcnt, (float*)d_out);
}

// Round 7
// 53.557 us; speedup vs baseline: 3.9688x; 1.3094x over previous
//
#include <hip/hip_runtime.h>

#define B_SZ 256
#define D_SZ 256
#define M_SZ 65536
#define C_SZ 1000
#define TEMP 0.05f
#define EPSF 1e-6f

#define NBLK_SORT 32
#define CHUNK (M_SZ / NBLK_SORT)   // 2048 labels per sort block

// ---- ws layout (bytes) ----
#define OFF_FCT     0          // float[D_SZ*C_SZ] = 1,024,000 B (transposed, pre-scaled)
#define OFF_NUMS    1024000    // int[C_SZ]
#define OFF_OFFS    1028000    // int[C_SZ]
#define OFF_ACC     1032000    // float[2]
#define OFF_LCNT    1032008    // int[1] loss ticket
#define OFF_COUNTS  1032064    // int[NBLK_SORT*C_SZ] = 128,000 B
#define OFF_MEMB    1160064    // int[M_SZ] = 262,144 B (end 1,422,208)

// Pass 1: per-block private LDS histogram (no global atomics). Block 0 zeroes
// cross-kernel accumulators (visible to later kernels via kernel boundary).
__launch_bounds__(1024)
__global__ void k_hist(const int* __restrict__ labels, int* __restrict__ counts,
                       float* __restrict__ acc, int* __restrict__ lcnt) {
    __shared__ int h[C_SZ];
    int t = threadIdx.x, b = blockIdx.x;
    if (t < C_SZ) h[t] = 0;
    if (b == 0 && t == 0) { acc[0] = 0.f; acc[1] = 0.f; lcnt[0] = 0; }
    __syncthreads();
    int start = b * CHUNK;
    #pragma unroll
    for (int k = 0; k < CHUNK / 1024; ++k)
        atomicAdd(&h[labels[start + k * 1024 + t]], 1);  // LDS atomic
    __syncthreads();
    if (t < C_SZ) counts[b * C_SZ + t] = h[t];
}

// Pass 2: scatter; each block redundantly computes the global scan (parallel,
// cheap) so no single-block scan dispatch. Block 0 publishes nums/offs.
__launch_bounds__(1024)
__global__ void k_scatter(const int* __restrict__ labels, const int* __restrict__ counts,
                          int* __restrict__ nums, int* __restrict__ offs,
                          int* __restrict__ members) {
    __shared__ int sc[1024];
    __shared__ int cur[C_SZ];
    int t = threadIdx.x, b = blockIdx.x;
    int tot = 0, mybase = 0;
    if (t < C_SZ) {
        #pragma unroll
        for (int bb = 0; bb < NBLK_SORT; ++bb) {
            int v = counts[bb * C_SZ + t];
            tot += v;
            if (bb < b) mybase += v;
        }
    }
    sc[t] = tot;
    __syncthreads();
    for (int d = 1; d < 1024; d <<= 1) {
        int v = (t >= d) ? sc[t - d] : 0;
        __syncthreads();
        sc[t] += v;
        __syncthreads();
    }
    if (t < C_SZ) {
        int e = sc[t] - tot;
        cur[t] = e + mybase;
        if (b == 0) { nums[t] = tot; offs[t] = e; }
    }
    __syncthreads();
    int start = b * CHUNK;
    #pragma unroll
    for (int k = 0; k < CHUNK / 1024; ++k) {
        int m = start + k * 1024 + t;
        int pos = atomicAdd(&cur[labels[m]], 1);  // LDS atomic
        members[pos] = m;
    }
}

// One block per class: sum member rows, 8-way unrolled for MLP. Writes
// transposed + pre-scaled: fct[d*C + c] = sum / (TEMP * max(n,1)).
__launch_bounds__(256)
__global__ void k_classsum(const float* __restrict__ features,
                           const int* __restrict__ members,
                           const int* __restrict__ offs,
                           const int* __restrict__ nums,
                           float* __restrict__ fct) {
    int c = blockIdx.x;
    int t = threadIdx.x;
    int beg = offs[c], n = nums[c];
    float a0 = 0.f, a1 = 0.f, a2 = 0.f, a3 = 0.f;
    float a4 = 0.f, a5 = 0.f, a6 = 0.f, a7 = 0.f;
    int i = 0;
    for (; i + 8 <= n; i += 8) {
        int r0 = members[beg + i + 0];
        int r1 = members[beg + i + 1];
        int r2 = members[beg + i + 2];
        int r3 = members[beg + i + 3];
        int r4 = members[beg + i + 4];
        int r5 = members[beg + i + 5];
        int r6 = members[beg + i + 6];
        int r7 = members[beg + i + 7];
        a0 += features[(size_t)r0 * D_SZ + t];
        a1 += features[(size_t)r1 * D_SZ + t];
        a2 += features[(size_t)r2 * D_SZ + t];
        a3 += features[(size_t)r3 * D_SZ + t];
        a4 += features[(size_t)r4 * D_SZ + t];
        a5 += features[(size_t)r5 * D_SZ + t];
        a6 += features[(size_t)r6 * D_SZ + t];
        a7 += features[(size_t)r7 * D_SZ + t];
    }
    for (; i < n; ++i) a0 += features[(size_t)members[beg + i] * D_SZ + t];
    float s = ((a0 + a1) + (a2 + a3)) + ((a4 + a5) + (a6 + a7));
    float scale = 1.0f / (TEMP * (float)(n > 0 ? n : 1));
    fct[(size_t)t * C_SZ + c] = s * scale;
}

// One block (1024 thr) per TWO batch rows (2r, 2r+1); thread t = class t.
// (R4's proven version: 128 blocks -> good occupancy; fct reads coalesced.)
__launch_bounds__(1024)
__global__ void k_loss(const float* __restrict__ feat,
                       const float* __restrict__ fct,
                       const int* __restrict__ nums,
                       const float* __restrict__ soft,
                       const int* __restrict__ indexes,
                       const int* __restrict__ labels,
                       const int* __restrict__ bil,
                       const int* __restrict__ cur_epoch,
                       float* __restrict__ acc, int* __restrict__ lcnt,
                       float* __restrict__ out) {
    __shared__ float xs0[D_SZ], xs1[D_SZ];
    __shared__ float wred[16], wred2[16];
    __shared__ float bc0, bc1;
    __shared__ int tgt0, tgt1, sr0, sr1;

    int t = threadIdx.x;
    int lane = t & 63, wid = t >> 6;
    int r0 = blockIdx.x * 2;

    if (t == 0) {
        tgt0 = labels[indexes[r0]];
        tgt1 = labels[indexes[r0 + 1]];
        sr0 = bil[r0];
        sr1 = bil[r0 + 1];
    }

    // ---- normalize rows 2r,2r+1 (contiguous 512 floats) ----
    float v = (t < 512) ? feat[(size_t)r0 * D_SZ + t] : 0.f;
    float s = v * v;
    #pragma unroll
    for (int o = 32; o; o >>= 1) s += __shfl_down(s, o);
    if (lane == 0) wred[wid] = s;  // waves 0-3 = row0, 4-7 = row1
    __syncthreads();
    if (t == 0) {
        bc0 = fmaxf(sqrtf(wred[0] + wred[1] + wred[2] + wred[3]), 1e-12f);
        bc1 = fmaxf(sqrtf(wred[4] + wred[5] + wred[6] + wred[7]), 1e-12f);
    }
    __syncthreads();
    if (t < 256) xs0[t] = v / bc0;
    else if (t < 512) xs1[t - 256] = v / bc1;
    __syncthreads();

    // ---- sim + exp for class t, both rows ----
    float a0 = 0.f, a1 = 0.f;
    if (t < C_SZ) {
        #pragma unroll 8
        for (int i = 0; i < D_SZ; ++i) {
            float f = fct[(size_t)i * C_SZ + t];  // coalesced across lanes
            a0 = fmaf(xs0[i], f, a0);
            a1 = fmaf(xs1[i], f, a1);
        }
    }
    float mk = (t < C_SZ && nums[t] > 0) ? 1.f : 0.f;
    float e0 = mk * __expf(a0);
    float e1 = mk * __expf(a1);

    // ---- denominators over classes (both rows at once) ----
    float s0 = e0, s1 = e1;
    #pragma unroll
    for (int o = 32; o; o >>= 1) {
        s0 += __shfl_down(s0, o);
        s1 += __shfl_down(s1, o);
    }
    if (lane == 0) { wred[wid] = s0; wred2[wid] = s1; }
    __syncthreads();
    if (t == 0) {
        float z0 = 0.f, z1 = 0.f;
        #pragma unroll
        for (int i = 0; i < 16; ++i) { z0 += wred[i]; z1 += wred2[i]; }
        bc0 = z0; bc1 = z1;
    }
    __syncthreads();
    float inv0 = 1.0f / (bc0 + EPSF);
    float inv1 = 1.0f / (bc1 + EPSF);

    // ---- loss partials ----
    float p1 = 0.f, p2 = 0.f;
    if (t < C_SZ) {
        float lp0 = __logf(e0 * inv0 + EPSF);
        float lp1 = __logf(e1 * inv1 + EPSF);
        p2 = -(soft[(size_t)sr0 * C_SZ + t] * lp0 + soft[(size_t)sr1 * C_SZ + t] * lp1);
        if (t == tgt0) p1 -= lp0;
        if (t == tgt1) p1 -= lp1;
    }
    #pragma unroll
    for (int o = 32; o; o >>= 1) {
        p1 += __shfl_down(p1, o);
        p2 += __shfl_down(p2, o);
    }
    __syncthreads();
    if (lane == 0) { wred[wid] = p1; wred2[wid] = p2; }
    __syncthreads();
    if (t == 0) {
        float z1 = 0.f, z2 = 0.f;
        #pragma unroll
        for (int i = 0; i < 16; ++i) { z1 += wred[i]; z2 += wred2[i]; }
        atomicAdd(&acc[0], z1);
        atomicAdd(&acc[1], z2);
        __threadfence();
        int done = atomicAdd(lcnt, 1);
        if (done == (int)gridDim.x - 1) {
            float l1 = atomicAdd(&acc[0], 0.f) / (float)B_SZ;
            float l2 = atomicAdd(&acc[1], 0.f) / (float)B_SZ;
            out[0] = (cur_epoch[0] == 0) ? l1 : 0.5f * (l1 + l2);
        }
    }
}

extern "C" void kernel_launch(void* const* d_in, const int* in_sizes, int n_in,
                              void* d_out, int out_size, void* d_ws, size_t ws_size,
                              hipStream_t stream) {
    const float* feat     = (const float*)d_in[0];
    const float* features = (const float*)d_in[1];
    const float* soft     = (const float*)d_in[2];
    const int* indexes    = (const int*)d_in[3];
    const int* labels     = (const int*)d_in[4];
    const int* bil        = (const int*)d_in[5];
    const int* cur_epoch  = (const int*)d_in[6];

    char* ws = (char*)d_ws;
    float* fct   = (float*)(ws + OFF_FCT);
    int* nums    = (int*)(ws + OFF_NUMS);
    int* offs    = (int*)(ws + OFF_OFFS);
    float* acc   = (float*)(ws + OFF_ACC);
    int* lcnt    = (int*)(ws + OFF_LCNT);
    int* counts  = (int*)(ws + OFF_COUNTS);
    int* members = (int*)(ws + OFF_MEMB);

    k_hist<<<NBLK_SORT, 1024, 0, stream>>>(labels, counts, acc, lcnt);
    k_scatter<<<NBLK_SORT, 1024, 0, stream>>>(labels, counts, nums, offs, members);
    k_classsum<<<C_SZ, 256, 0, stream>>>(features, members, offs, nums, fct);
    k_loss<<<B_SZ / 2, 1024, 0, stream>>>(feat, fct, nums, soft, indexes, labels,
                                          bil, cur_epoch, acc, lcnt, (float*)d_out);
}